// Round 13
// baseline (107.381 us; speedup 1.0000x reference)
//
#include <hip/hip_runtime.h>
#include <hip/hip_bf16.h>

#define B_   2
#define S_   2048
#define D_   768
#define H_   12
#define DK_  64
#define R_   (B_*S_)   // 4096 rows total
#define LOG2E_OVER8 0.18033688011112042f

typedef __attribute__((ext_vector_type(8))) short short8;
typedef __attribute__((ext_vector_type(4))) float f32x4;

__device__ __forceinline__ short f2b(float f) {
  union { float f; unsigned u; } x; x.f = f;
  unsigned r = x.u + 0x7fffu + ((x.u >> 16) & 1u);
  return (short)(r >> 16);
}

__device__ __forceinline__ unsigned cvt_pk_bf16(float lo, float hi) {
  unsigned r;
  asm("v_cvt_pk_bf16_f32 %0, %1, %2" : "=v"(r) : "v"(lo), "v"(hi));
  return r;
}

__device__ __forceinline__ void gl_lds16(const short* g, short* l) {
  __builtin_amdgcn_global_load_lds(
      (const __attribute__((address_space(1))) void*)g,
      (__attribute__((address_space(3))) void*)l, 16, 0, 0);
}

// ---------------- fp32 -> bf16 conversion (x + 4 weights) ----------------
__global__ void cvt_kernel(const float* __restrict__ x,
                           const float* __restrict__ wq, const float* __restrict__ wk,
                           const float* __restrict__ wv, const float* __restrict__ wo,
                           short* __restrict__ xb, short* __restrict__ wb) {
  const int XQ = R_ * D_ / 4;
  const int WQ = D_ * D_ / 4;
  int idx = blockIdx.x * blockDim.x + threadIdx.x;
  const float* src; short* dst; int off;
  if (idx < XQ) { src = x; dst = xb; off = idx; }
  else {
    int wi = idx - XQ; int w = wi / WQ; off = wi - w * WQ;
    if      (w == 0) { src = wq; dst = wb; }
    else if (w == 1) { src = wk; dst = wb + D_*D_; }
    else if (w == 2) { src = wv; dst = wb + 2*D_*D_; }
    else             { src = wo; dst = wb + 3*D_*D_; }
  }
  float4 v = ((const float4*)src)[off];
  short4 o;
  o.x = f2b(v.x); o.y = f2b(v.y); o.z = f2b(v.z); o.w = f2b(v.w);
  ((short4*)dst)[off] = o;
}

// ------- QKV projection: 128x128, dbuf (v10-proven loop); VT via LDS transpose ------
__launch_bounds__(256)
__global__ void qkv_gemm_kernel(const short* __restrict__ xb, const short* __restrict__ wb,
                                const float* __restrict__ bq, const float* __restrict__ bk,
                                const float* __restrict__ bv,
                                short* __restrict__ Qw, short* __restrict__ Kw,
                                short* __restrict__ VTw) {
  __shared__ short As[2][128 * 32];
  __shared__ short Bs[2][128 * 32];
  __shared__ short Tt[64][136];     // V-tile transpose staging (e-half x mm), 17.4KB
  const int which = blockIdx.z;
  const short* W = wb + which * (D_ * D_);
  const float* bias = (which == 0) ? bq : (which == 1) ? bk : bv;
  const int n0 = blockIdx.x * 128, m0 = blockIdx.y * 128;
  const int t = threadIdx.x, l = t & 63, w = t >> 6;
  const int wr = w >> 1, wc = w & 1;

  f32x4 acc[4][4] = {};
  const int srow = t >> 2, sseg = (t & 3) * 8;

#define GSTAGE(buf, k0) do { \
    gl_lds16(xb + (m0 + srow) * D_ + (k0) + sseg,      &As[buf][t * 8]); \
    gl_lds16(xb + (m0 + 64 + srow) * D_ + (k0) + sseg, &As[buf][(t + 256) * 8]); \
    gl_lds16(W  + (n0 + srow) * D_ + (k0) + sseg,      &Bs[buf][t * 8]); \
    gl_lds16(W  + (n0 + 64 + srow) * D_ + (k0) + sseg, &Bs[buf][(t + 256) * 8]); \
  } while (0)

  GSTAGE(0, 0);
  __syncthreads();
  int cur = 0;
  for (int k0 = 0; k0 < D_; k0 += 32) {
    if (k0 + 32 < D_) GSTAGE(cur ^ 1, k0 + 32);
    short8 a[4], b[4];
#pragma unroll
    for (int i = 0; i < 4; i++)
      a[i] = *(const short8*)&As[cur][(wr * 64 + i * 16 + (l & 15)) * 32 + (l >> 4) * 8];
#pragma unroll
    for (int i = 0; i < 4; i++)
      b[i] = *(const short8*)&Bs[cur][(wc * 64 + i * 16 + (l & 15)) * 32 + (l >> 4) * 8];
#pragma unroll
    for (int i = 0; i < 4; i++)
#pragma unroll
      for (int j = 0; j < 4; j++)
        acc[i][j] = __builtin_amdgcn_mfma_f32_16x16x32_bf16(a[i], b[j], acc[i][j], 0, 0, 0);
    __syncthreads();
    cur ^= 1;
  }
#undef GSTAGE

  if (which != 2) {
    // Q/K epilogue: 32B-contiguous per 16 lanes (coalesced enough)
#pragma unroll
    for (int i = 0; i < 4; i++) {
#pragma unroll
      for (int j2 = 0; j2 < 4; j2++) {
        int mm = m0 + wr * 64 + i * 16 + (l >> 4) * 4 + j2;
        int bidx = mm >> 11, s = mm & 2047;
#pragma unroll
        for (int nj = 0; nj < 4; nj++) {
          int e = n0 + wc * 64 + nj * 16 + (l & 15);
          float val = acc[i][nj][j2] + bias[e];
          int h = e >> 6, dk = e & 63;
          int bh = bidx * H_ + h;
          if (which == 0) Qw[(bh * S_ + s) * DK_ + dk] = f2b(val * LOG2E_OVER8);
          else            Kw[(bh * S_ + s) * DK_ + dk] = f2b(val);
        }
      }
    }
  } else {
    // V epilogue: LDS transpose -> coalesced 64B runs along S.
    // Two passes over e-halves p=0,1 (waves with wc==p hold that half).
    const int bidx = m0 >> 11;
    const int s0 = m0 & 2047;
#pragma unroll
    for (int p = 0; p < 2; p++) {
      __syncthreads();                       // Tt free (or prev pass consumed)
      if (wc == p) {
#pragma unroll
        for (int nj = 0; nj < 4; nj++) {
          int row = nj * 16 + (l & 15);      // e_rel in [0,64)
          float be = bias[n0 + p * 64 + row];
#pragma unroll
          for (int i = 0; i < 4; i++) {
            int colb = wr * 64 + i * 16 + (l >> 4) * 4;   // mm_local base (j2-packed)
            short4 pk;
            pk.x = f2b(acc[i][nj][0] + be);
            pk.y = f2b(acc[i][nj][1] + be);
            pk.z = f2b(acc[i][nj][2] + be);
            pk.w = f2b(acc[i][nj][3] + be);
            *(short4*)&Tt[row][colb] = pk;
          }
        }
      }
      __syncthreads();
      // store: thread t -> e_rel = t>>2, s-quarter q = t&3 (32 shorts = 64B contiguous)
      {
        int e_rel = t >> 2, q = t & 3;
        int e = n0 + p * 64 + e_rel;
        int h = e >> 6, dk = e & 63;
        short* dst = VTw + ((bidx * H_ + h) * DK_ + dk) * S_ + s0 + q * 32;
#pragma unroll
        for (int k = 0; k < 4; k++)
          *(short8*)(dst + 8 * k) = *(const short8*)&Tt[e_rel][q * 32 + 8 * k];
      }
    }
  }
}

// ---------------- flash attention v10 (verbatim: 43.4 us proven) ----------
#define KVB   32
#define SHALF 1024
__launch_bounds__(256, 3)
__global__ void attn_kernel(const short* __restrict__ Qw, const short* __restrict__ Kw,
                            const short* __restrict__ VTw, short* __restrict__ ctx) {
  __shared__ short Ksh[2][2][KVB * DK_];   // [stream][buf][32 rows][64]
  __shared__ short Vsh[2][2][KVB * DK_];   // [stream][buf] pair-packed rows

  const int t = threadIdx.x, l = t & 63, w = t >> 6;
  const int s = w >> 1, qh = w & 1;
  const int L = blockIdx.y * 32 + blockIdx.x;
  const int xcd = L & 7, idx = L >> 3;
  const int bh = xcd * 3 + (idx >> 5);
  const int qblk = idx & 31;
  const int q0 = qblk * 64 + qh * 32;
  const int bq = bh / H_, h = bh - bq * H_;
  const short* Qh = Qw + bh * S_ * DK_;
  const short* Kh = Kw + (bh * S_ + s * SHALF) * DK_;
  const short* Vh = VTw + bh * DK_ * S_ + s * SHALF;

  const int tt = t & 127;
  const int kr0 = tt >> 3, kc0 = tt & 7;
  const int koff0 = kr0 * DK_ + ((kc0 ^ (kr0 & 7)) << 3);
  const int vc8 = (tt & 7) ^ ((tt >> 3) & 7);
  const int vr0 = 2 * (tt >> 3) + (vc8 >> 2);
  const int voff0 = vr0 * S_ + ((vc8 & 3) << 3);

#define STAGE(buf, kt) do { \
    gl_lds16(Kh + (kt) * DK_ + koff0,        &Ksh[s][buf][tt * 8]); \
    gl_lds16(Kh + (kt) * DK_ + koff0 + 1024, &Ksh[s][buf][tt * 8 + 1024]); \
    gl_lds16(Vh + (kt) + voff0,              &Vsh[s][buf][tt * 8]); \
    gl_lds16(Vh + (kt) + voff0 + 32 * S_,    &Vsh[s][buf][tt * 8 + 1024]); \
  } while (0)

  short8 qf[2][2];
#pragma unroll
  for (int mi = 0; mi < 2; mi++)
#pragma unroll
    for (int ks = 0; ks < 2; ks++)
      qf[mi][ks] = *(const short8*)&Qh[(q0 + 16 * mi + (l & 15)) * DK_ + ks * 32 + (l >> 4) * 8];

  f32x4 acc_o[2][4] = {};
  float l_run[2] = {0.f, 0.f};

  STAGE(0, 0);
  __syncthreads();
  int cur = 0;

  for (int kt = 0; kt < SHALF; kt += KVB) {
    if (kt + KVB < SHALF) STAGE(cur ^ 1, kt + KVB);

    f32x4 acc_s[2][2] = {};
    __builtin_amdgcn_s_setprio(1);
#pragma unroll
    for (int ni = 0; ni < 2; ni++) {
      int r = (l & 15) + 16 * ni;
#pragma unroll
      for (int ks = 0; ks < 2; ks++) {
        int cc = (l >> 4) + 4 * ks;
        short8 kf = *(const short8*)&Ksh[s][cur][r * DK_ + ((cc ^ (r & 7)) << 3)];
        acc_s[0][ni] = __builtin_amdgcn_mfma_f32_16x16x32_bf16(kf, qf[0][ks], acc_s[0][ni], 0, 0, 0);
        acc_s[1][ni] = __builtin_amdgcn_mfma_f32_16x16x32_bf16(kf, qf[1][ks], acc_s[1][ni], 0, 0, 0);
      }
    }
    __builtin_amdgcn_s_setprio(0);

#pragma unroll
    for (int mi = 0; mi < 2; mi++) {
      float sum = 0.f;
#pragma unroll
      for (int ni = 0; ni < 2; ni++)
#pragma unroll
        for (int j = 0; j < 4; j++) {
          float p = __builtin_amdgcn_exp2f(acc_s[mi][ni][j]);
          acc_s[mi][ni][j] = p;
          sum += p;
        }
      l_run[mi] += sum;
    }

    union PK { unsigned u[4]; short8 v; } pa0, pa1;
    pa0.u[0] = cvt_pk_bf16(acc_s[0][0][0], acc_s[0][0][1]);
    pa0.u[1] = cvt_pk_bf16(acc_s[0][0][2], acc_s[0][0][3]);
    pa0.u[2] = cvt_pk_bf16(acc_s[0][1][0], acc_s[0][1][1]);
    pa0.u[3] = cvt_pk_bf16(acc_s[0][1][2], acc_s[0][1][3]);
    pa1.u[0] = cvt_pk_bf16(acc_s[1][0][0], acc_s[1][0][1]);
    pa1.u[1] = cvt_pk_bf16(acc_s[1][0][2], acc_s[1][0][3]);
    pa1.u[2] = cvt_pk_bf16(acc_s[1][1][0], acc_s[1][1][1]);
    pa1.u[3] = cvt_pk_bf16(acc_s[1][1][2], acc_s[1][1][3]);

    __builtin_amdgcn_s_setprio(1);
    {
      const int cc = l >> 4;
      union V8 { short4 h[2]; short8 v; };
#pragma unroll
      for (int nd = 0; nd < 4; nd++) {
        int vr = (l & 15) + 16 * nd, rp = vr >> 1;
        int ph0 = (((vr & 1) << 2) | (cc >> 1)) ^ (rp & 7);
        int ph1 = (((vr & 1) << 2) | (2 + (cc >> 1))) ^ (rp & 7);
        V8 vf;
        vf.h[0] = *(const short4*)&Vsh[s][cur][rp * 64 + ph0 * 8 + (cc & 1) * 4];
        vf.h[1] = *(const short4*)&Vsh[s][cur][rp * 64 + ph1 * 8 + (cc & 1) * 4];
        acc_o[0][nd] = __builtin_amdgcn_mfma_f32_16x16x32_bf16(pa0.v, vf.v, acc_o[0][nd], 0, 0, 0);
        acc_o[1][nd] = __builtin_amdgcn_mfma_f32_16x16x32_bf16(pa1.v, vf.v, acc_o[1][nd], 0, 0, 0);
      }
    }
    __builtin_amdgcn_s_setprio(0);

    __syncthreads();
    cur ^= 1;
  }

#pragma unroll
  for (int mi = 0; mi < 2; mi++) {
    l_run[mi] += __shfl_xor(l_run[mi], 16);
    l_run[mi] += __shfl_xor(l_run[mi], 32);
  }

  __syncthreads();
  float* Oshf = (float*)&Ksh[0][0][0];
  float* Lsh  = (float*)&Vsh[0][0][0];
  if (s == 1) {
#pragma unroll
    for (int mi = 0; mi < 2; mi++)
#pragma unroll
      for (int nd = 0; nd < 4; nd++)
#pragma unroll
        for (int j = 0; j < 4; j++)
          Oshf[qh * 2048 + (16 * mi + (l >> 4) * 4 + j) * 64 + (l & 15) + 16 * nd] = acc_o[mi][nd][j];
    if (l < 16) {
      Lsh[(qh * 2 + 0) * 16 + l] = l_run[0];
      Lsh[(qh * 2 + 1) * 16 + l] = l_run[1];
    }
  }
  __syncthreads();
  if (s == 0) {
#pragma unroll
    for (int mi = 0; mi < 2; mi++) {
#pragma unroll
      for (int j = 0; j < 4; j++) {
        int src = ((l >> 4) << 2) + j;
        float llo = __shfl(l_run[mi], src);
        float lhi = Lsh[(qh * 2 + mi) * 16 + src];
        float inv = 1.f / (llo + lhi);
        int srow = q0 + 16 * mi + src;
#pragma unroll
        for (int nd = 0; nd < 4; nd++) {
          float ohi = Oshf[qh * 2048 + (16 * mi + src) * 64 + (l & 15) + 16 * nd];
          float val = (acc_o[mi][nd][j] + ohi) * inv;
          ctx[(bq * S_ + srow) * D_ + h * DK_ + (l & 15) + 16 * nd] = f2b(val);
        }
      }
    }
  }
#undef STAGE
}

// ---------------- output projection (128x128, dbuf — v10 verbatim) ----------------
__launch_bounds__(256)
__global__ void oproj_kernel(const short* __restrict__ ctx, const short* __restrict__ Wo,
                             const float* __restrict__ bo, float* __restrict__ out) {
  __shared__ short As[2][128 * 32];
  __shared__ short Bs[2][128 * 32];
  const int n0 = blockIdx.x * 128, m0 = blockIdx.y * 128;
  const int t = threadIdx.x, l = t & 63, w = t >> 6;
  const int wr = w >> 1, wc = w & 1;

  f32x4 acc[4][4] = {};
  const int srow = t >> 2, sseg = (t & 3) * 8;

#define GSTAGE(buf, k0) do { \
    gl_lds16(ctx + (m0 + srow) * D_ + (k0) + sseg,      &As[buf][t * 8]); \
    gl_lds16(ctx + (m0 + 64 + srow) * D_ + (k0) + sseg, &As[buf][(t + 256) * 8]); \
    gl_lds16(Wo  + (n0 + srow) * D_ + (k0) + sseg,      &Bs[buf][t * 8]); \
    gl_lds16(Wo  + (n0 + 64 + srow) * D_ + (k0) + sseg, &Bs[buf][(t + 256) * 8]); \
  } while (0)

  GSTAGE(0, 0);
  __syncthreads();
  int cur = 0;
  for (int k0 = 0; k0 < D_; k0 += 32) {
    if (k0 + 32 < D_) GSTAGE(cur ^ 1, k0 + 32);
    short8 a[4], b[4];
#pragma unroll
    for (int i = 0; i < 4; i++)
      a[i] = *(const short8*)&As[cur][(wr * 64 + i * 16 + (l & 15)) * 32 + (l >> 4) * 8];
#pragma unroll
    for (int i = 0; i < 4; i++)
      b[i] = *(const short8*)&Bs[cur][(wc * 64 + i * 16 + (l & 15)) * 32 + (l >> 4) * 8];
#pragma unroll
    for (int i = 0; i < 4; i++)
#pragma unroll
      for (int j = 0; j < 4; j++)
        acc[i][j] = __builtin_amdgcn_mfma_f32_16x16x32_bf16(a[i], b[j], acc[i][j], 0, 0, 0);
    __syncthreads();
    cur ^= 1;
  }
#undef GSTAGE

#pragma unroll
  for (int i = 0; i < 4; i++) {
#pragma unroll
    for (int j2 = 0; j2 < 4; j2++) {
      int mm = m0 + wr * 64 + i * 16 + (l >> 4) * 4 + j2;
#pragma unroll
      for (int nj = 0; nj < 4; nj++) {
        int e = n0 + wc * 64 + nj * 16 + (l & 15);
        out[mm * D_ + e] = acc[i][nj][j2] + bo[e];
      }
    }
  }
}

extern "C" void kernel_launch(void* const* d_in, const int* in_sizes, int n_in,
                              void* d_out, int out_size, void* d_ws, size_t ws_size,
                              hipStream_t stream) {
  (void)in_sizes; (void)n_in; (void)out_size; (void)ws_size;
  const float* x  = (const float*)d_in[0];
  const float* wq = (const float*)d_in[1];
  const float* bq = (const float*)d_in[2];
  const float* wk = (const float*)d_in[3];
  const float* bk = (const float*)d_in[4];
  const float* wv = (const float*)d_in[5];
  const float* bv = (const float*)d_in[6];
  const float* wo = (const float*)d_in[7];
  const float* bo = (const float*)d_in[8];
  float* out = (float*)d_out;

  short* xb  = (short*)d_ws;            // R*D bf16
  short* wb  = xb + R_ * D_;            // 4*D*D bf16 (q,k,v,o)
  short* Qw  = wb + 4 * D_ * D_;        // [B,H,S,DK]
  short* Kw  = Qw + R_ * D_;            // [B,H,S,DK]
  short* VTw = Kw + R_ * D_;            // [B,H,DK,S]
  short* ctx = VTw + R_ * D_;           // [B,S,D]

  cvt_kernel<<<5376, 256, 0, stream>>>(x, wq, wk, wv, wo, xb, wb);
  qkv_gemm_kernel<<<dim3(6, 32, 3), 256, 0, stream>>>(xb, wb, bq, bk, bv, Qw, Kw, VTw);
  attn_kernel<<<dim3(32, 24), 256, 0, stream>>>(Qw, Kw, VTw, ctx);
  oproj_kernel<<<dim3(6, 32), 256, 0, stream>>>(ctx, wb + 3 * D_ * D_, bo, out);
}

// Round 14
// 102.660 us; speedup vs baseline: 1.0460x; 1.0460x over previous
//
#include <hip/hip_runtime.h>
#include <hip/hip_bf16.h>

#define B_   2
#define S_   2048
#define D_   768
#define H_   12
#define DK_  64
#define R_   (B_*S_)   // 4096 rows total
#define LOG2E_OVER8 0.18033688011112042f

typedef __attribute__((ext_vector_type(8))) short short8;
typedef __attribute__((ext_vector_type(4))) float f32x4;

__device__ __forceinline__ short f2b(float f) {
  union { float f; unsigned u; } x; x.f = f;
  unsigned r = x.u + 0x7fffu + ((x.u >> 16) & 1u);
  return (short)(r >> 16);
}

__device__ __forceinline__ unsigned cvt_pk_bf16(float lo, float hi) {
  unsigned r;
  asm("v_cvt_pk_bf16_f32 %0, %1, %2" : "=v"(r) : "v"(lo), "v"(hi));
  return r;
}

__device__ __forceinline__ void gl_lds16(const short* g, short* l) {
  __builtin_amdgcn_global_load_lds(
      (const __attribute__((address_space(1))) void*)g,
      (__attribute__((address_space(3))) void*)l, 16, 0, 0);
}

// ---------------- fp32 -> bf16 conversion (x + 4 weights) ----------------
__global__ void cvt_kernel(const float* __restrict__ x,
                           const float* __restrict__ wq, const float* __restrict__ wk,
                           const float* __restrict__ wv, const float* __restrict__ wo,
                           short* __restrict__ xb, short* __restrict__ wb) {
  const int XQ = R_ * D_ / 4;
  const int WQ = D_ * D_ / 4;
  int idx = blockIdx.x * blockDim.x + threadIdx.x;
  const float* src; short* dst; int off;
  if (idx < XQ) { src = x; dst = xb; off = idx; }
  else {
    int wi = idx - XQ; int w = wi / WQ; off = wi - w * WQ;
    if      (w == 0) { src = wq; dst = wb; }
    else if (w == 1) { src = wk; dst = wb + D_*D_; }
    else if (w == 2) { src = wv; dst = wb + 2*D_*D_; }
    else             { src = wo; dst = wb + 3*D_*D_; }
  }
  float4 v = ((const float4*)src)[off];
  short4 o;
  o.x = f2b(v.x); o.y = f2b(v.y); o.z = f2b(v.z); o.w = f2b(v.w);
  ((short4*)dst)[off] = o;
}

// ------- QKV projection: 128x128 tile, BK=64 (12 steps), swizzled LDS, dbuf -------
// LDS tile [128 rows][64 cols] bf16: 8 chunks of 8 elems per row; chunk c holds
// global col-chunk (c ^ (r&7)) (linear dest + pre-swizzled src + swizzled read).
__launch_bounds__(256)
__global__ void qkv_gemm_kernel(const short* __restrict__ xb, const short* __restrict__ wb,
                                const float* __restrict__ bq, const float* __restrict__ bk,
                                const float* __restrict__ bv,
                                short* __restrict__ Qw, short* __restrict__ Kw,
                                short* __restrict__ VTw) {
  __shared__ short As[2][128 * 64];   // 32KB
  __shared__ short Bs[2][128 * 64];   // 32KB
  const int which = blockIdx.z;
  const short* W = wb + which * (D_ * D_);
  const float* bias = (which == 0) ? bq : (which == 1) ? bk : bv;
  const int n0 = blockIdx.x * 128, m0 = blockIdx.y * 128;
  const int t = threadIdx.x, l = t & 63, w = t >> 6;
  const int wr = w >> 1, wc = w & 1;

  f32x4 acc[4][4] = {};

  // staging: 1024 chunks per array; thread t takes i = t + 256j, j<4.
  // chunk i: row r = i>>3 (= (t>>3) + 32j), c = i&7; src col-chunk = c ^ (r&7).
  const int sr0 = t >> 3, sc0 = t & 7;
  const int soff = sr0 * D_ + ((sc0 ^ (sr0 & 7)) << 3);   // j adds 32 rows: (r&7) invariant

#define GSTAGE(buf, k0) do { \
    _Pragma("unroll") \
    for (int j = 0; j < 4; j++) { \
      gl_lds16(xb + (m0 + 32 * j) * D_ + soff + (k0), &As[buf][(t + 256 * j) * 8]); \
      gl_lds16(W  + (n0 + 32 * j) * D_ + soff + (k0), &Bs[buf][(t + 256 * j) * 8]); \
    } \
  } while (0)

  GSTAGE(0, 0);
  __syncthreads();
  int cur = 0;
  for (int k0 = 0; k0 < D_; k0 += 64) {
    if (k0 + 64 < D_) GSTAGE(cur ^ 1, k0 + 64);
#pragma unroll
    for (int kk = 0; kk < 2; kk++) {
      short8 a[4], b[4];
#pragma unroll
      for (int i = 0; i < 4; i++) {
        int R = wr * 64 + i * 16 + (l & 15);
        int g = kk * 4 + (l >> 4);
        a[i] = *(const short8*)&As[cur][R * 64 + ((g ^ (R & 7)) << 3)];
      }
#pragma unroll
      for (int i = 0; i < 4; i++) {
        int R = wc * 64 + i * 16 + (l & 15);
        int g = kk * 4 + (l >> 4);
        b[i] = *(const short8*)&Bs[cur][R * 64 + ((g ^ (R & 7)) << 3)];
      }
#pragma unroll
      for (int i = 0; i < 4; i++)
#pragma unroll
        for (int j = 0; j < 4; j++)
          acc[i][j] = __builtin_amdgcn_mfma_f32_16x16x32_bf16(a[i], b[j], acc[i][j], 0, 0, 0);
    }
    __syncthreads();
    cur ^= 1;
  }
#undef GSTAGE

#pragma unroll
  for (int i = 0; i < 4; i++) {
#pragma unroll
    for (int j2 = 0; j2 < 4; j2++) {
      int mm = m0 + wr * 64 + i * 16 + (l >> 4) * 4 + j2;
      int bidx = mm >> 11, s = mm & 2047;
#pragma unroll
      for (int nj = 0; nj < 4; nj++) {
        int e = n0 + wc * 64 + nj * 16 + (l & 15);
        float val = acc[i][nj][j2] + bias[e];
        int h = e >> 6, dk = e & 63;
        int bh = bidx * H_ + h;
        if (which == 0)      Qw[(bh * S_ + s) * DK_ + dk] = f2b(val * LOG2E_OVER8);
        else if (which == 1) Kw[(bh * S_ + s) * DK_ + dk] = f2b(val);
        else                 VTw[(bh * DK_ + dk) * S_ + s] = f2b(val);
      }
    }
  }
}

// ---------------- flash attention v10 (verbatim: 43.4 us proven) ----------
#define KVB   32
#define SHALF 1024
__launch_bounds__(256, 3)
__global__ void attn_kernel(const short* __restrict__ Qw, const short* __restrict__ Kw,
                            const short* __restrict__ VTw, short* __restrict__ ctx) {
  __shared__ short Ksh[2][2][KVB * DK_];   // [stream][buf][32 rows][64]
  __shared__ short Vsh[2][2][KVB * DK_];   // [stream][buf] pair-packed rows

  const int t = threadIdx.x, l = t & 63, w = t >> 6;
  const int s = w >> 1, qh = w & 1;
  const int L = blockIdx.y * 32 + blockIdx.x;
  const int xcd = L & 7, idx = L >> 3;
  const int bh = xcd * 3 + (idx >> 5);
  const int qblk = idx & 31;
  const int q0 = qblk * 64 + qh * 32;
  const int bq = bh / H_, h = bh - bq * H_;
  const short* Qh = Qw + bh * S_ * DK_;
  const short* Kh = Kw + (bh * S_ + s * SHALF) * DK_;
  const short* Vh = VTw + bh * DK_ * S_ + s * SHALF;

  const int tt = t & 127;
  const int kr0 = tt >> 3, kc0 = tt & 7;
  const int koff0 = kr0 * DK_ + ((kc0 ^ (kr0 & 7)) << 3);
  const int vc8 = (tt & 7) ^ ((tt >> 3) & 7);
  const int vr0 = 2 * (tt >> 3) + (vc8 >> 2);
  const int voff0 = vr0 * S_ + ((vc8 & 3) << 3);

#define STAGE(buf, kt) do { \
    gl_lds16(Kh + (kt) * DK_ + koff0,        &Ksh[s][buf][tt * 8]); \
    gl_lds16(Kh + (kt) * DK_ + koff0 + 1024, &Ksh[s][buf][tt * 8 + 1024]); \
    gl_lds16(Vh + (kt) + voff0,              &Vsh[s][buf][tt * 8]); \
    gl_lds16(Vh + (kt) + voff0 + 32 * S_,    &Vsh[s][buf][tt * 8 + 1024]); \
  } while (0)

  short8 qf[2][2];
#pragma unroll
  for (int mi = 0; mi < 2; mi++)
#pragma unroll
    for (int ks = 0; ks < 2; ks++)
      qf[mi][ks] = *(const short8*)&Qh[(q0 + 16 * mi + (l & 15)) * DK_ + ks * 32 + (l >> 4) * 8];

  f32x4 acc_o[2][4] = {};
  float l_run[2] = {0.f, 0.f};

  STAGE(0, 0);
  __syncthreads();
  int cur = 0;

  for (int kt = 0; kt < SHALF; kt += KVB) {
    if (kt + KVB < SHALF) STAGE(cur ^ 1, kt + KVB);

    f32x4 acc_s[2][2] = {};
    __builtin_amdgcn_s_setprio(1);
#pragma unroll
    for (int ni = 0; ni < 2; ni++) {
      int r = (l & 15) + 16 * ni;
#pragma unroll
      for (int ks = 0; ks < 2; ks++) {
        int cc = (l >> 4) + 4 * ks;
        short8 kf = *(const short8*)&Ksh[s][cur][r * DK_ + ((cc ^ (r & 7)) << 3)];
        acc_s[0][ni] = __builtin_amdgcn_mfma_f32_16x16x32_bf16(kf, qf[0][ks], acc_s[0][ni], 0, 0, 0);
        acc_s[1][ni] = __builtin_amdgcn_mfma_f32_16x16x32_bf16(kf, qf[1][ks], acc_s[1][ni], 0, 0, 0);
      }
    }
    __builtin_amdgcn_s_setprio(0);

#pragma unroll
    for (int mi = 0; mi < 2; mi++) {
      float sum = 0.f;
#pragma unroll
      for (int ni = 0; ni < 2; ni++)
#pragma unroll
        for (int j = 0; j < 4; j++) {
          float p = __builtin_amdgcn_exp2f(acc_s[mi][ni][j]);
          acc_s[mi][ni][j] = p;
          sum += p;
        }
      l_run[mi] += sum;
    }

    union PK { unsigned u[4]; short8 v; } pa0, pa1;
    pa0.u[0] = cvt_pk_bf16(acc_s[0][0][0], acc_s[0][0][1]);
    pa0.u[1] = cvt_pk_bf16(acc_s[0][0][2], acc_s[0][0][3]);
    pa0.u[2] = cvt_pk_bf16(acc_s[0][1][0], acc_s[0][1][1]);
    pa0.u[3] = cvt_pk_bf16(acc_s[0][1][2], acc_s[0][1][3]);
    pa1.u[0] = cvt_pk_bf16(acc_s[1][0][0], acc_s[1][0][1]);
    pa1.u[1] = cvt_pk_bf16(acc_s[1][0][2], acc_s[1][0][3]);
    pa1.u[2] = cvt_pk_bf16(acc_s[1][1][0], acc_s[1][1][1]);
    pa1.u[3] = cvt_pk_bf16(acc_s[1][1][2], acc_s[1][1][3]);

    __builtin_amdgcn_s_setprio(1);
    {
      const int cc = l >> 4;
      union V8 { short4 h[2]; short8 v; };
#pragma unroll
      for (int nd = 0; nd < 4; nd++) {
        int vr = (l & 15) + 16 * nd, rp = vr >> 1;
        int ph0 = (((vr & 1) << 2) | (cc >> 1)) ^ (rp & 7);
        int ph1 = (((vr & 1) << 2) | (2 + (cc >> 1))) ^ (rp & 7);
        V8 vf;
        vf.h[0] = *(const short4*)&Vsh[s][cur][rp * 64 + ph0 * 8 + (cc & 1) * 4];
        vf.h[1] = *(const short4*)&Vsh[s][cur][rp * 64 + ph1 * 8 + (cc & 1) * 4];
        acc_o[0][nd] = __builtin_amdgcn_mfma_f32_16x16x32_bf16(pa0.v, vf.v, acc_o[0][nd], 0, 0, 0);
        acc_o[1][nd] = __builtin_amdgcn_mfma_f32_16x16x32_bf16(pa1.v, vf.v, acc_o[1][nd], 0, 0, 0);
      }
    }
    __builtin_amdgcn_s_setprio(0);

    __syncthreads();
    cur ^= 1;
  }

#pragma unroll
  for (int mi = 0; mi < 2; mi++) {
    l_run[mi] += __shfl_xor(l_run[mi], 16);
    l_run[mi] += __shfl_xor(l_run[mi], 32);
  }

  __syncthreads();
  float* Oshf = (float*)&Ksh[0][0][0];
  float* Lsh  = (float*)&Vsh[0][0][0];
  if (s == 1) {
#pragma unroll
    for (int mi = 0; mi < 2; mi++)
#pragma unroll
      for (int nd = 0; nd < 4; nd++)
#pragma unroll
        for (int j = 0; j < 4; j++)
          Oshf[qh * 2048 + (16 * mi + (l >> 4) * 4 + j) * 64 + (l & 15) + 16 * nd] = acc_o[mi][nd][j];
    if (l < 16) {
      Lsh[(qh * 2 + 0) * 16 + l] = l_run[0];
      Lsh[(qh * 2 + 1) * 16 + l] = l_run[1];
    }
  }
  __syncthreads();
  if (s == 0) {
#pragma unroll
    for (int mi = 0; mi < 2; mi++) {
#pragma unroll
      for (int j = 0; j < 4; j++) {
        int src = ((l >> 4) << 2) + j;
        float llo = __shfl(l_run[mi], src);
        float lhi = Lsh[(qh * 2 + mi) * 16 + src];
        float inv = 1.f / (llo + lhi);
        int srow = q0 + 16 * mi + src;
#pragma unroll
        for (int nd = 0; nd < 4; nd++) {
          float ohi = Oshf[qh * 2048 + (16 * mi + src) * 64 + (l & 15) + 16 * nd];
          float val = (acc_o[mi][nd][j] + ohi) * inv;
          ctx[(bq * S_ + srow) * D_ + h * DK_ + (l & 15) + 16 * nd] = f2b(val);
        }
      }
    }
  }
#undef STAGE
}

// ------- output projection: 64x128 tile, BK=64 (12 steps), swizzled LDS, dbuf ------
__launch_bounds__(256)
__global__ void oproj_kernel(const short* __restrict__ ctx, const short* __restrict__ Wo,
                             const float* __restrict__ bo, float* __restrict__ out) {
  __shared__ short As[2][64 * 64];    // 16KB
  __shared__ short Bs[2][128 * 64];   // 32KB
  const int n0 = blockIdx.x * 128, m0 = blockIdx.y * 64;
  const int t = threadIdx.x, l = t & 63, w = t >> 6;

  f32x4 acc[4][2] = {};

  const int sr0 = t >> 3, sc0 = t & 7;
  const int soff = sr0 * D_ + ((sc0 ^ (sr0 & 7)) << 3);

#define GSTAGE(buf, k0) do { \
    _Pragma("unroll") \
    for (int j = 0; j < 2; j++) \
      gl_lds16(ctx + (m0 + 32 * j) * D_ + soff + (k0), &As[buf][(t + 256 * j) * 8]); \
    _Pragma("unroll") \
    for (int j = 0; j < 4; j++) \
      gl_lds16(Wo + (n0 + 32 * j) * D_ + soff + (k0), &Bs[buf][(t + 256 * j) * 8]); \
  } while (0)

  GSTAGE(0, 0);
  __syncthreads();
  int cur = 0;
  for (int k0 = 0; k0 < D_; k0 += 64) {
    if (k0 + 64 < D_) GSTAGE(cur ^ 1, k0 + 64);
#pragma unroll
    for (int kk = 0; kk < 2; kk++) {
      short8 a[4], b[2];
#pragma unroll
      for (int i = 0; i < 4; i++) {
        int R = i * 16 + (l & 15);
        int g = kk * 4 + (l >> 4);
        a[i] = *(const short8*)&As[cur][R * 64 + ((g ^ (R & 7)) << 3)];
      }
#pragma unroll
      for (int nj = 0; nj < 2; nj++) {
        int R = w * 32 + nj * 16 + (l & 15);
        int g = kk * 4 + (l >> 4);
        b[nj] = *(const short8*)&Bs[cur][R * 64 + ((g ^ (R & 7)) << 3)];
      }
#pragma unroll
      for (int i = 0; i < 4; i++)
#pragma unroll
        for (int nj = 0; nj < 2; nj++)
          acc[i][nj] = __builtin_amdgcn_mfma_f32_16x16x32_bf16(a[i], b[nj], acc[i][nj], 0, 0, 0);
    }
    __syncthreads();
    cur ^= 1;
  }
#undef GSTAGE

#pragma unroll
  for (int i = 0; i < 4; i++) {
#pragma unroll
    for (int j2 = 0; j2 < 4; j2++) {
      int mm = m0 + i * 16 + (l >> 4) * 4 + j2;
#pragma unroll
      for (int nj = 0; nj < 2; nj++) {
        int e = n0 + w * 32 + nj * 16 + (l & 15);
        out[mm * D_ + e] = acc[i][nj][j2] + bo[e];
      }
    }
  }
}

extern "C" void kernel_launch(void* const* d_in, const int* in_sizes, int n_in,
                              void* d_out, int out_size, void* d_ws, size_t ws_size,
                              hipStream_t stream) {
  (void)in_sizes; (void)n_in; (void)out_size; (void)ws_size;
  const float* x  = (const float*)d_in[0];
  const float* wq = (const float*)d_in[1];
  const float* bq = (const float*)d_in[2];
  const float* wk = (const float*)d_in[3];
  const float* bk = (const float*)d_in[4];
  const float* wv = (const float*)d_in[5];
  const float* bv = (const float*)d_in[6];
  const float* wo = (const float*)d_in[7];
  const float* bo = (const float*)d_in[8];
  float* out = (float*)d_out;

  short* xb  = (short*)d_ws;            // R*D bf16
  short* wb  = xb + R_ * D_;            // 4*D*D bf16 (q,k,v,o)
  short* Qw  = wb + 4 * D_ * D_;        // [B,H,S,DK]
  short* Kw  = Qw + R_ * D_;            // [B,H,S,DK]
  short* VTw = Kw + R_ * D_;            // [B,H,DK,S]
  short* ctx = VTw + R_ * D_;           // [B,S,D]

  cvt_kernel<<<5376, 256, 0, stream>>>(x, wq, wk, wv, wo, xb, wb);
  qkv_gemm_kernel<<<dim3(6, 32, 3), 256, 0, stream>>>(xb, wb, bq, bk, bv, Qw, Kw, VTw);
  attn_kernel<<<dim3(32, 24), 256, 0, stream>>>(Qw, Kw, VTw, ctx);
  oproj_kernel<<<dim3(6, 64), 256, 0, stream>>>(ctx, wb + 3 * D_ * D_, bo, out);
}